// Round 4
// baseline (51.916 us; speedup 1.0000x reference)
//
#include <hip/hip_runtime.h>
#include <math.h>

// AttnPool: score = h@W + b -> per-segment softmax (segments = sorted batch ids)
//           out[b] = sum_i softmax_w[i] * h[i]  for rows i in segment b.
//
// Single dispatch, single pass over h, fully coalesced, register-resident:
//   - one 64-lane wave per segment (4 waves/block).
//   - segment bounds: ONE vectorized binary search per wave (even lanes
//     search lower_bound(seg), odd lanes lower_bound(seg+1), lockstep),
//     results broadcast via __shfl. No boundary kernel, no workspace.
//   - chunk of 8 rows: load i covers row-pair (2i, 2i+1): lanes 0-31 read
//     dims 4l..4l+3 of row 2i, lanes 32-63 of row 2i+1 -> one contiguous
//     1KB block per load instruction.
//   - scores: per-lane 4-dim partial dot + 5-step __shfl_xor butterfly per
//     32-lane half; online softmax; weighted accumulate from the SAME
//     registers (h is read exactly once from HBM).
//   - explicit A/B register ping-pong keeps next chunk's loads in flight.

constexpr int D = 128;
constexpr int SEG_PER_BLOCK = 4;

__global__ __launch_bounds__(256, 6) void attnpool_kernel(
    const float* __restrict__ h,
    const int*   __restrict__ batch,
    const float* __restrict__ W,
    const float* __restrict__ bias,
    float*       __restrict__ out,
    int N, int B)
{
    const int tid  = threadIdx.x;
    const int wave = tid >> 6;
    const int lane = tid & 63;
    const int half = lane >> 5;            // 0: even rows, 1: odd rows
    const int col  = (lane & 31) << 2;     // this lane's 4 dims: col..col+3
    const int seg  = blockIdx.x * SEG_PER_BLOCK + wave;
    if (seg >= B) return;

    // ---- bounds: one lockstep binary search (even lanes: seg, odd: seg+1) ----
    const int target = seg + (lane & 1);
    int lo = 0, hi = N;
    while (lo < hi) {
        const int mid = (lo + hi) >> 1;
        if (batch[mid] < target) lo = mid + 1; else hi = mid;
    }
    const int s   = __shfl(lo, 0);
    const int e   = __shfl(lo, 1);
    const int len = e - s;

    if (len <= 0) {
        if (half == 0) *(float4*)(out + (size_t)seg * D + col) = make_float4(0.f, 0.f, 0.f, 0.f);
        return;
    }

    const float4 w4     = *(const float4*)(W + col);
    const float  bconst = bias[0];
    const float* hbase  = h + (size_t)s * D + col;   // row r -> hbase + r*D

    float  m = -INFINITY, l = 0.f;
    float4 acc = make_float4(0.f, 0.f, 0.f, 0.f);

    auto loadChunk = [&](float4* V, int cbase) {
        #pragma unroll
        for (int i = 0; i < 4; ++i) {
            const int r = cbase + 2 * i + half;
            V[i] = (r < len) ? *(const float4*)(hbase + (size_t)r * D)
                             : make_float4(0.f, 0.f, 0.f, 0.f);
        }
    };

    auto computeChunk = [&](const float4* V, int cbase) {
        float p[4];
        #pragma unroll
        for (int i = 0; i < 4; ++i)
            p[i] = fmaf(V[i].w, w4.w, fmaf(V[i].z, w4.z, fmaf(V[i].y, w4.y, V[i].x * w4.x)));
        #pragma unroll
        for (int i = 0; i < 4; ++i) {
            #pragma unroll
            for (int o = 1; o <= 16; o <<= 1) p[i] += __shfl_xor(p[i], o);
            const int r = cbase + 2 * i + half;          // uniform per half
            p[i] = (r < len) ? (p[i] + bconst) : -INFINITY;
        }
        float lm = fmaxf(fmaxf(p[0], p[1]), fmaxf(p[2], p[3]));
        lm = fmaxf(lm, __shfl_xor(lm, 32));
        const float mnew  = fmaxf(m, lm);                // finite: >=1 valid row
        const float scale = __expf(m - mnew);            // 0 on first chunk

        float ev[4], ssum = 0.f;
        #pragma unroll
        for (int i = 0; i < 4; ++i) { ev[i] = __expf(p[i] - mnew); ssum += ev[i]; }
        const float ls = ssum + __shfl_xor(ssum, 32);

        l = fmaf(l, scale, ls);
        acc.x *= scale; acc.y *= scale; acc.z *= scale; acc.w *= scale;
        #pragma unroll
        for (int i = 0; i < 4; ++i) {
            acc.x = fmaf(ev[i], V[i].x, acc.x);
            acc.y = fmaf(ev[i], V[i].y, acc.y);
            acc.z = fmaf(ev[i], V[i].z, acc.z);
            acc.w = fmaf(ev[i], V[i].w, acc.w);
        }
        m = mnew;
    };

    float4 A[4], Bv[4];
    loadChunk(A, 0);
    int base = 0;
    for (;;) {
        loadChunk(Bv, base + 8);       // prefetch next chunk (zeros if past end)
        computeChunk(A, base);
        base += 8;
        if (base >= len) break;
        loadChunk(A, base + 8);
        computeChunk(Bv, base);
        base += 8;
        if (base >= len) break;
    }

    // combine halves (lane l and l^32 hold the same 4 dims), normalize, store
    acc.x += __shfl_xor(acc.x, 32);
    acc.y += __shfl_xor(acc.y, 32);
    acc.z += __shfl_xor(acc.z, 32);
    acc.w += __shfl_xor(acc.w, 32);
    const float inv = 1.f / l;
    acc.x *= inv; acc.y *= inv; acc.z *= inv; acc.w *= inv;
    if (half == 0) *(float4*)(out + (size_t)seg * D + col) = acc;
}

extern "C" void kernel_launch(void* const* d_in, const int* in_sizes, int n_in,
                              void* d_out, int out_size, void* d_ws, size_t ws_size,
                              hipStream_t stream) {
    const float* h     = (const float*)d_in[0];
    const int*   batch = (const int*)  d_in[1];
    const float* W     = (const float*)d_in[2];
    const float* bias  = (const float*)d_in[3];
    float*       out   = (float*)d_out;

    const int N = in_sizes[0] / D;   // 500000
    const int B = out_size / D;      // 10000

    const int grid = (B + SEG_PER_BLOCK - 1) / SEG_PER_BLOCK;
    attnpool_kernel<<<grid, 256, 0, stream>>>(h, batch, W, bias, out, N, B);
}

// Round 5
// 49.659 us; speedup vs baseline: 1.0454x; 1.0454x over previous
//
#include <hip/hip_runtime.h>
#include <math.h>

// AttnPool: score = h@W + b -> per-segment softmax (segments = sorted batch ids)
//           out[b] = sum_i softmax_w[i] * h[i]  for rows i in segment b.
//
// Two dispatches:
//   1) seg_bounds_kernel: vectorized (8 entries/thread) boundary scan of the
//      sorted batch array -> seg_start[B+1] in d_ws.
//   2) attnpool_kernel (R3 winner, unchanged): one 64-lane wave per segment,
//      single coalesced register-resident pass over h with online softmax.

constexpr int D = 128;
constexpr int SEG_PER_BLOCK = 4;
constexpr int EPT = 8;           // batch entries per thread in bounds kernel

// seg_start[t] = first row index i with batch[i] >= t, for t in [0, B].
__global__ void seg_bounds_kernel(const int* __restrict__ batch,
                                  int* __restrict__ seg_start, int N, int B) {
    const int i0 = (blockIdx.x * blockDim.x + threadIdx.x) * EPT;
    if (i0 >= N) return;

    int prev = (i0 == 0) ? -1 : batch[i0 - 1];

    if (i0 + EPT <= N) {
        const int4 v0 = *(const int4*)(batch + i0);
        const int4 v1 = *(const int4*)(batch + i0 + 4);
        const int v[EPT] = {v0.x, v0.y, v0.z, v0.w, v1.x, v1.y, v1.z, v1.w};
        #pragma unroll
        for (int j = 0; j < EPT; ++j) {
            for (int t = prev + 1; t <= v[j]; ++t) seg_start[t] = i0 + j;
            prev = v[j];
        }
        if (i0 + EPT == N)
            for (int t = prev + 1; t <= B; ++t) seg_start[t] = N;
    } else {
        for (int j = 0; j < EPT && i0 + j < N; ++j) {
            const int b = batch[i0 + j];
            for (int t = prev + 1; t <= b; ++t) seg_start[t] = i0 + j;
            prev = b;
        }
        if (i0 + EPT >= N)   // this thread covers the final element
            for (int t = prev + 1; t <= B; ++t) seg_start[t] = N;
    }
}

__global__ __launch_bounds__(256, 6) void attnpool_kernel(
    const float* __restrict__ h,
    const float* __restrict__ W,
    const float* __restrict__ bias,
    const int*   __restrict__ seg_start,
    float*       __restrict__ out,
    int N, int B)
{
    const int tid  = threadIdx.x;
    const int wave = tid >> 6;
    const int lane = tid & 63;
    const int half = lane >> 5;            // 0: even rows, 1: odd rows
    const int col  = (lane & 31) << 2;     // this lane's 4 dims: col..col+3
    const int seg  = blockIdx.x * SEG_PER_BLOCK + wave;
    if (seg >= B) return;

    const int s   = seg_start[seg];
    const int e   = seg_start[seg + 1];
    const int len = e - s;

    if (len <= 0) {
        if (half == 0) *(float4*)(out + (size_t)seg * D + col) = make_float4(0.f, 0.f, 0.f, 0.f);
        return;
    }

    const float4 w4     = *(const float4*)(W + col);
    const float  bconst = bias[0];
    const float* hbase  = h + (size_t)s * D + col;   // row r -> hbase + r*D

    float  m = -INFINITY, l = 0.f;
    float4 acc = make_float4(0.f, 0.f, 0.f, 0.f);

    auto loadChunk = [&](float4* V, int cbase) {
        #pragma unroll
        for (int i = 0; i < 4; ++i) {
            const int r = cbase + 2 * i + half;
            V[i] = (r < len) ? *(const float4*)(hbase + (size_t)r * D)
                             : make_float4(0.f, 0.f, 0.f, 0.f);
        }
    };

    auto computeChunk = [&](const float4* V, int cbase) {
        float p[4];
        #pragma unroll
        for (int i = 0; i < 4; ++i)
            p[i] = fmaf(V[i].w, w4.w, fmaf(V[i].z, w4.z, fmaf(V[i].y, w4.y, V[i].x * w4.x)));
        #pragma unroll
        for (int i = 0; i < 4; ++i) {
            #pragma unroll
            for (int o = 1; o <= 16; o <<= 1) p[i] += __shfl_xor(p[i], o);
            const int r = cbase + 2 * i + half;          // uniform per half
            p[i] = (r < len) ? (p[i] + bconst) : -INFINITY;
        }
        float lm = fmaxf(fmaxf(p[0], p[1]), fmaxf(p[2], p[3]));
        lm = fmaxf(lm, __shfl_xor(lm, 32));
        const float mnew  = fmaxf(m, lm);                // finite: >=1 valid row
        const float scale = __expf(m - mnew);            // 0 on first chunk

        float ev[4], ssum = 0.f;
        #pragma unroll
        for (int i = 0; i < 4; ++i) { ev[i] = __expf(p[i] - mnew); ssum += ev[i]; }
        const float ls = ssum + __shfl_xor(ssum, 32);

        l = fmaf(l, scale, ls);
        acc.x *= scale; acc.y *= scale; acc.z *= scale; acc.w *= scale;
        #pragma unroll
        for (int i = 0; i < 4; ++i) {
            acc.x = fmaf(ev[i], V[i].x, acc.x);
            acc.y = fmaf(ev[i], V[i].y, acc.y);
            acc.z = fmaf(ev[i], V[i].z, acc.z);
            acc.w = fmaf(ev[i], V[i].w, acc.w);
        }
        m = mnew;
    };

    float4 A[4], Bv[4];
    loadChunk(A, 0);
    int base = 0;
    for (;;) {
        loadChunk(Bv, base + 8);       // prefetch next chunk (zeros if past end)
        computeChunk(A, base);
        base += 8;
        if (base >= len) break;
        loadChunk(A, base + 8);
        computeChunk(Bv, base);
        base += 8;
        if (base >= len) break;
    }

    // combine halves (lane l and l^32 hold the same 4 dims), normalize, store
    acc.x += __shfl_xor(acc.x, 32);
    acc.y += __shfl_xor(acc.y, 32);
    acc.z += __shfl_xor(acc.z, 32);
    acc.w += __shfl_xor(acc.w, 32);
    const float inv = 1.f / l;
    acc.x *= inv; acc.y *= inv; acc.z *= inv; acc.w *= inv;
    if (half == 0) *(float4*)(out + (size_t)seg * D + col) = acc;
}

extern "C" void kernel_launch(void* const* d_in, const int* in_sizes, int n_in,
                              void* d_out, int out_size, void* d_ws, size_t ws_size,
                              hipStream_t stream) {
    const float* h     = (const float*)d_in[0];
    const int*   batch = (const int*)  d_in[1];
    const float* W     = (const float*)d_in[2];
    const float* bias  = (const float*)d_in[3];
    float*       out   = (float*)d_out;

    const int N = in_sizes[0] / D;   // 500000
    const int B = out_size / D;      // 10000

    int* seg_start = (int*)d_ws;     // (B+1) ints; ws is plenty

    const int bthreads = (N + EPT - 1) / EPT;
    seg_bounds_kernel<<<(bthreads + 255) / 256, 256, 0, stream>>>(batch, seg_start, N, B);

    const int grid = (B + SEG_PER_BLOCK - 1) / SEG_PER_BLOCK;
    attnpool_kernel<<<grid, 256, 0, stream>>>(h, W, bias, seg_start, out, N, B);
}